// Round 7
// baseline (701.558 us; speedup 1.0000x reference)
//
#include <hip/hip_runtime.h>

static constexpr int DIN = 512;
static constexpr int DOUT = 256;
static constexpr int CAP = 128;   // max in-degree (Poisson(32): P(any>128) ~ 1e-17)
static constexpr int GRID = 2048; // 8 blocks/CU x 256 CU co-resident
static constexpr int LEAVES = 64;

typedef __attribute__((ext_vector_type(8))) short short8;
typedef __attribute__((ext_vector_type(4))) float f32x4;

__device__ inline unsigned short f2bf(float f) {
  unsigned int b = __float_as_uint(f);
  unsigned int r = (b + 0x7fffu + ((b >> 16) & 1u)) >> 16;
  return (unsigned short)r;
}
__device__ inline float bf_lo(unsigned int packed) { return __uint_as_float(packed << 16); }
__device__ inline float bf_hi(unsigned int packed) { return __uint_as_float(packed & 0xffff0000u); }

__device__ inline short8 cvt8(const float4 a, const float4 b) {
  short8 o;
  o[0] = (short)f2bf(a.x); o[1] = (short)f2bf(a.y);
  o[2] = (short)f2bf(a.z); o[3] = (short)f2bf(a.w);
  o[4] = (short)f2bf(b.x); o[5] = (short)f2bf(b.y);
  o[6] = (short)f2bf(b.z); o[7] = (short)f2bf(b.w);
  return o;
}

struct Params {
  const float* x;
  const int* ei;
  const float* ew;
  const float* W;
  float* out;
  unsigned short* h1b;
  unsigned short* wbb;
  float* deg;    // deg[n] ++ cursor[n], contiguous (zeroed in prep)
  int* cursor;
  uint2* bucket;
  int* bars;     // 2 x 66 ints: [root, gen, leaf0..63], zeroed in prep
  int n, E;
};

// ---- fast grid barrier: two-level counters + sense flag ----
__device__ inline void gbar(int* bar) {
  __syncthreads();
  if (threadIdx.x == 0) {
    __threadfence();
    const int leaf = blockIdx.x & (LEAVES - 1);
    const int per_leaf = (int)gridDim.x / LEAVES;
    if (__hip_atomic_fetch_add(&bar[2 + leaf], 1, __ATOMIC_ACQ_REL,
                               __HIP_MEMORY_SCOPE_AGENT) == per_leaf - 1) {
      if (__hip_atomic_fetch_add(&bar[0], 1, __ATOMIC_ACQ_REL,
                                 __HIP_MEMORY_SCOPE_AGENT) == LEAVES - 1) {
        __hip_atomic_store(&bar[1], 1, __ATOMIC_RELEASE, __HIP_MEMORY_SCOPE_AGENT);
      }
    }
    while (__hip_atomic_load(&bar[1], __ATOMIC_ACQUIRE, __HIP_MEMORY_SCOPE_AGENT) == 0)
      __builtin_amdgcn_s_sleep(2);
    __threadfence();
  }
  __syncthreads();
}

// ---- prep (separate dispatch): zero deg/cursor/bars; W -> bf16 ----
__global__ __launch_bounds__(256) void k_prep(Params p) {
  const int gid = blockIdx.x * 256 + threadIdx.x;
  const int stride = gridDim.x * 256;
  int* dz = (int*)p.deg;  // deg[n] ++ cursor[n]
  for (int i = gid; i < 2 * p.n; i += stride) dz[i] = 0;
  if (gid < 132) p.bars[gid] = 0;
  const int wgroups = DOUT * DIN / 8;
  for (int i = gid; i < wgroups; i += stride) {
    const float4* src = (const float4*)(p.W + (size_t)i * 8);
    float4 a = src[0], b = src[1];
    *(short8*)(p.wbb + (size_t)i * 8) = cvt8(a, b);
  }
}

// ---- phase 1a: edges: deg[src] += w; bucket[dst] append (src,w) ----
__device__ inline void dev_edges(const Params& p) {
  const int stride = (int)gridDim.x * 256;
  for (int e = blockIdx.x * 256 + threadIdx.x; e < p.E; e += stride) {
    int srcv = p.ei[e];
    int dstv = p.ei[p.E + e];
    float w = p.ew[e];
    atomicAdd(&p.deg[srcv], w);
    int pos = atomicAdd(&p.cursor[dstv], 1);
    if (pos < CAP) {
      uint2 v;
      v.x = (unsigned)srcv;
      v.y = __float_as_uint(w);
      p.bucket[(size_t)dstv * CAP + pos] = v;
    }
  }
}

// ---- phase 1b: GEMM mainloop, UNSCALED h1b. One 16x64 tile per block ----
__device__ inline void dev_gemm(const Params& p) {
  const int lane = threadIdx.x & 63;
  const int wv = threadIdx.x >> 6;
  const int bm = (blockIdx.x >> 2) * 16;
  if (bm >= p.n) return;
  const int colb = (blockIdx.x & 3) * 64 + wv * 16;
  const int r = lane & 15;
  const int kg = lane >> 4;
  f32x4 acc = {};
  const float* arow = p.x + (size_t)(bm + r) * DIN + kg * 8;
  const unsigned short* brow = p.wbb + (size_t)(colb + r) * DIN + kg * 8;
#pragma unroll
  for (int k0 = 0; k0 < DIN; k0 += 32) {
    float4 a0 = *(const float4*)(arow + k0);
    float4 a1 = *(const float4*)(arow + k0 + 4);
    short8 av = cvt8(a0, a1);
    short8 bv = *(const short8*)(brow + k0);
    acc = __builtin_amdgcn_mfma_f32_16x16x32_bf16(av, bv, acc, 0, 0, 0);
  }
#pragma unroll
  for (int i = 0; i < 4; ++i) {
    int row = bm + kg * 4 + i;
    p.h1b[(size_t)row * DOUT + colb + r] = f2bf(acc[i]);
  }
}

// ---- phase 2: scale h1b rows in place by rsqrt(1+deg[row]) ----
__device__ inline void dev_scale(const Params& p) {
  const int lane = threadIdx.x & 63;
  const int wv = threadIdx.x >> 6;
  const int row = blockIdx.x * 4 + wv;
  if (row >= p.n) return;
  const float sr = __frsqrt_rn(1.0f + p.deg[row]);
  unsigned short* rp = p.h1b + (size_t)row * DOUT + lane * 4;
  uint2 v = *(uint2*)rp;
  uint2 o;
  o.x = ((unsigned)f2bf(sr * bf_lo(v.x))) | (((unsigned)f2bf(sr * bf_hi(v.x))) << 16);
  o.y = ((unsigned)f2bf(sr * bf_lo(v.y))) | (((unsigned)f2bf(sr * bf_hi(v.y))) << 16);
  *(uint2*)rp = o;
}

// ---- gather chunk: up to 64 edges in (sv,wl) across the wave, depth-4 ----
__device__ inline void gather_chunk(float acc[8], int sv, float wl, int c,
                                    const unsigned short* h1b, int cl, int half) {
  const int npair = ((c + 7) >> 3) << 2;  // pad edges to mult of 8 (pads: src=0,w=0)
  for (int j = 0; j < npair; j += 4) {
    uint4 rbuf[4];
#pragma unroll
    for (int u = 0; u < 4; ++u) {
      int src = __shfl(sv, 2 * (j + u) + half);
      rbuf[u] = *(const uint4*)(h1b + (size_t)src * DOUT + cl * 8);
    }
#pragma unroll
    for (int u = 0; u < 4; ++u) {
      float w = __shfl(wl, 2 * (j + u) + half);
      acc[0] = fmaf(w, bf_lo(rbuf[u].x), acc[0]);
      acc[1] = fmaf(w, bf_hi(rbuf[u].x), acc[1]);
      acc[2] = fmaf(w, bf_lo(rbuf[u].y), acc[2]);
      acc[3] = fmaf(w, bf_hi(rbuf[u].y), acc[3]);
      acc[4] = fmaf(w, bf_lo(rbuf[u].z), acc[4]);
      acc[5] = fmaf(w, bf_hi(rbuf[u].z), acc[5]);
      acc[6] = fmaf(w, bf_lo(rbuf[u].w), acc[6]);
      acc[7] = fmaf(w, bf_hi(rbuf[u].w), acc[7]);
    }
  }
}

// ---- phase 3: gather: out[d] = s[d]*(h1s[d] + sum w*h1s[src]); 1 dst/wave ----
__device__ inline void dev_gather(const Params& p) {
  const int lane = threadIdx.x & 63;
  const int wv = threadIdx.x >> 6;
  const int cl = lane & 31;
  const int half = lane >> 5;
  const int d = blockIdx.x * 4 + wv;
  if (d >= p.n) return;
  const int cnt = min(p.cursor[d], CAP);
  const uint4 selfv = *(const uint4*)(p.h1b + (size_t)d * DOUT + cl * 8);
  const float sd = __frsqrt_rn(1.0f + p.deg[d]);
  uint2 ev0; ev0.x = 0u; ev0.y = 0u;
  uint2 ev1; ev1.x = 0u; ev1.y = 0u;
  if (lane < cnt) ev0 = p.bucket[(size_t)d * CAP + lane];
  if (64 + lane < cnt) ev1 = p.bucket[(size_t)d * CAP + 64 + lane];

  float acc[8] = {};
  gather_chunk(acc, (int)ev0.x, __uint_as_float(ev0.y), min(cnt, 64), p.h1b, cl, half);
  if (cnt > 64)
    gather_chunk(acc, (int)ev1.x, __uint_as_float(ev1.y), cnt - 64, p.h1b, cl, half);

#pragma unroll
  for (int k = 0; k < 8; ++k) acc[k] += __shfl_xor(acc[k], 32);

  if (half == 0) {
    float4 o0v, o1v;
    o0v.x = sd * (bf_lo(selfv.x) + acc[0]);
    o0v.y = sd * (bf_hi(selfv.x) + acc[1]);
    o0v.z = sd * (bf_lo(selfv.y) + acc[2]);
    o0v.w = sd * (bf_hi(selfv.y) + acc[3]);
    o1v.x = sd * (bf_lo(selfv.z) + acc[4]);
    o1v.y = sd * (bf_hi(selfv.z) + acc[5]);
    o1v.z = sd * (bf_lo(selfv.w) + acc[6]);
    o1v.w = sd * (bf_hi(selfv.w) + acc[7]);
    float* op = p.out + (size_t)d * DOUT + cl * 8;
    *(float4*)op = o0v;
    *(float4*)(op + 4) = o1v;
  }
}

// ---- fused kernel: coop-launched for residency; hand-rolled barriers ----
__global__ __launch_bounds__(256, 8) void k_fused(Params p) {
  dev_edges(p);        // atomic latency overlaps with...
  dev_gemm(p);         // ...the MFMA mainloop (independent of deg/bucket)
  gbar(p.bars);        // deg, bucket, h1b(unscaled) now complete
  dev_scale(p);
  gbar(p.bars + 66);   // h1b scaled, visible everywhere
  dev_gather(p);
}

// ---- non-cooperative fallback ----
__global__ __launch_bounds__(256, 8) void k_p1(Params p) { dev_edges(p); dev_gemm(p); }
__global__ __launch_bounds__(256, 8) void k_p2(Params p) { dev_scale(p); }
__global__ __launch_bounds__(256, 8) void k_p3(Params p) { dev_gather(p); }

extern "C" void kernel_launch(void* const* d_in, const int* in_sizes, int n_in,
                              void* d_out, int out_size, void* d_ws, size_t ws_size,
                              hipStream_t stream) {
  Params p;
  p.x = (const float*)d_in[0];
  p.ei = (const int*)d_in[1];  // [2, E]: row0 = src, row1 = dst
  p.ew = (const float*)d_in[2];
  p.W = (const float*)d_in[3];
  p.out = (float*)d_out;
  p.n = in_sizes[0] / DIN;  // 8192
  p.E = in_sizes[2];        // 262144

  char* q = (char*)d_ws;
  auto alloc = [&](size_t bytes) {
    char* r = q;
    q += (bytes + 255) & ~(size_t)255;
    return r;
  };
  p.h1b = (unsigned short*)alloc((size_t)p.n * DOUT * 2);
  p.wbb = (unsigned short*)alloc((size_t)DOUT * DIN * 2);
  p.deg = (float*)alloc((size_t)p.n * 4 * 2);  // deg[n] ++ cursor[n]
  p.cursor = (int*)(p.deg + p.n);
  p.bucket = (uint2*)alloc((size_t)p.n * CAP * 8);
  p.bars = (int*)alloc(132 * 4);

  dim3 block(256);
  k_prep<<<256, block, 0, stream>>>(p);

  dim3 grid(GRID);
  void* args[] = {&p};
  hipError_t err =
      hipLaunchCooperativeKernel((const void*)k_fused, grid, block, args, 0, stream);
  if (err != hipSuccess) {
    k_p1<<<grid, block, 0, stream>>>(p);
    k_p2<<<grid, block, 0, stream>>>(p);
    k_p3<<<grid, block, 0, stream>>>(p);
  }
}

// Round 8
// 78.842 us; speedup vs baseline: 8.8983x; 8.8983x over previous
//
#include <hip/hip_runtime.h>

static constexpr int DIN = 512;
static constexpr int DOUT = 256;
static constexpr int CAP = 128;  // max in-degree capacity (Poisson(32): P(>128) ~ 1e-17)

typedef __attribute__((ext_vector_type(8))) short short8;
typedef __attribute__((ext_vector_type(4))) float f32x4;

__device__ inline unsigned short f2bf(float f) {
  unsigned int b = __float_as_uint(f);
  unsigned int r = (b + 0x7fffu + ((b >> 16) & 1u)) >> 16;
  return (unsigned short)r;
}
__device__ inline float bf_lo(unsigned int packed) { return __uint_as_float(packed << 16); }
__device__ inline float bf_hi(unsigned int packed) { return __uint_as_float(packed & 0xffff0000u); }

__device__ inline short8 cvt8(const float4 a, const float4 b) {
  short8 o;
  o[0] = (short)f2bf(a.x); o[1] = (short)f2bf(a.y);
  o[2] = (short)f2bf(a.z); o[3] = (short)f2bf(a.w);
  o[4] = (short)f2bf(b.x); o[5] = (short)f2bf(b.y);
  o[6] = (short)f2bf(b.z); o[7] = (short)f2bf(b.w);
  return o;
}

// ---- K1 (after memset of deg+cursor): edges + W->bf16 ----
// blocks [0, EB): one thread per edge. blocks [EB, EB+WB): W conversion.
__global__ __launch_bounds__(256) void k_edges(
    const int* __restrict__ ei, const float* __restrict__ ew,
    const float* __restrict__ W,
    float* __restrict__ deg, int* __restrict__ cursor,
    uint2* __restrict__ bucket, unsigned short* __restrict__ wbb,
    int E, int EB) {
  const int b = blockIdx.x;
  if (b < EB) {
    int e = b * 256 + threadIdx.x;
    if (e < E) {
      int srcv = ei[e];
      int dstv = ei[E + e];
      float w = ew[e];
      atomicAdd(&deg[srcv], w);
      int pos = atomicAdd(&cursor[dstv], 1);
      if (pos < CAP) {
        uint2 v;
        v.x = (unsigned)srcv;
        v.y = __float_as_uint(w);
        bucket[(size_t)dstv * CAP + pos] = v;
      }
    }
  } else {
    long i = (long)(b - EB) * 256 + threadIdx.x;  // short8 group
    const float4* src = (const float4*)(W + i * 8);
    float4 a = src[0], bb = src[1];
    *(short8*)(wbb + i * 8) = cvt8(a, bb);
  }
}

// ---- K2 GEMM: h1b[r][c] = bf16( rsqrt(1+deg[r]) * dot(x[r,:], W[c,:]) ) ----
// block = 4 waves; tile 16 rows x 256 cols (A read exactly once, inline cvt).
__global__ __launch_bounds__(256) void k_gemm_mfma(
    const float* __restrict__ x, const unsigned short* __restrict__ wbb,
    const float* __restrict__ deg, unsigned short* __restrict__ h1b) {
  const int lane = threadIdx.x & 63;
  const int wv = threadIdx.x >> 6;
  const int bm = blockIdx.x * 16;
  const int colb = wv * 64;
  const int r = lane & 15;
  const int kg = lane >> 4;
  f32x4 acc[4] = {};
  const float* arow = x + (size_t)(bm + r) * DIN + kg * 8;
  const unsigned short* brow0 = wbb + (size_t)(colb + r) * DIN + kg * 8;
#pragma unroll
  for (int k0 = 0; k0 < DIN; k0 += 32) {
    float4 a0 = *(const float4*)(arow + k0);
    float4 a1 = *(const float4*)(arow + k0 + 4);
    short8 av = cvt8(a0, a1);
#pragma unroll
    for (int nt = 0; nt < 4; ++nt) {
      short8 bv = *(const short8*)(brow0 + (size_t)nt * 16 * DIN + k0);
      acc[nt] = __builtin_amdgcn_mfma_f32_16x16x32_bf16(av, bv, acc[nt], 0, 0, 0);
    }
  }
#pragma unroll
  for (int i = 0; i < 4; ++i) {
    int row = bm + kg * 4 + i;
    float sr = __frsqrt_rn(1.0f + deg[row]);
#pragma unroll
    for (int nt = 0; nt < 4; ++nt) {
      h1b[(size_t)row * DOUT + colb + nt * 16 + r] = f2bf(sr * acc[nt][i]);
    }
  }
}

// ---- gather chunk (half-row): up to 64 edges in (sv,wl); 4 eslots x depth 8
// => 32 edges in flight per wave; pads (lanes >= c) carry sv=0,wl=0.
__device__ inline void gather_chunk_half(float acc[8], int sv, float wl, int c,
                                         const unsigned short* hbase, int cl,
                                         int eslot) {
  const int nb = (c + 3) >> 2;  // 4-edge batches
  for (int j0 = 0; j0 < nb; j0 += 8) {
    uint4 rbuf[8];
#pragma unroll
    for (int u = 0; u < 8; ++u) {
      int idx = (j0 + u) * 4 + eslot;  // <= 63 by construction
      int src = __shfl(sv, idx);
      rbuf[u] = *(const uint4*)(hbase + (size_t)src * DOUT + cl * 8);
    }
#pragma unroll
    for (int u = 0; u < 8; ++u) {
      float w = __shfl(wl, (j0 + u) * 4 + eslot);
      acc[0] = fmaf(w, bf_lo(rbuf[u].x), acc[0]);
      acc[1] = fmaf(w, bf_hi(rbuf[u].x), acc[1]);
      acc[2] = fmaf(w, bf_lo(rbuf[u].y), acc[2]);
      acc[3] = fmaf(w, bf_hi(rbuf[u].y), acc[3]);
      acc[4] = fmaf(w, bf_lo(rbuf[u].z), acc[4]);
      acc[5] = fmaf(w, bf_hi(rbuf[u].z), acc[5]);
      acc[6] = fmaf(w, bf_lo(rbuf[u].w), acc[6]);
      acc[7] = fmaf(w, bf_hi(rbuf[u].w), acc[7]);
    }
  }
}

// ---- K3/K4 gather over a 128-col half: out[d] = s*(h1[d] + sum w*h1[src]) --
// One wave per dst. 16 col-lanes (cl) x 4 edge-slots. Two serialized passes
// (colofs = 0 then 128) keep the active 2 MB half of h1b resident in every
// XCD's L2, so the E x 256B row reads hit local L2 instead of cross-XCD L3.
__global__ __launch_bounds__(256, 4) void k_gather_half(
    const unsigned short* __restrict__ h1b, const float* __restrict__ deg,
    const int* __restrict__ cursor, const uint2* __restrict__ bucket,
    float* __restrict__ out, int colofs) {
  const int lane = threadIdx.x & 63;
  const int wv = threadIdx.x >> 6;
  const int d = blockIdx.x * 4 + wv;
  const int cl = lane & 15;     // col-lane: cols colofs + cl*8 .. +7
  const int eslot = lane >> 4;  // 0..3
  const int cnt = min(cursor[d], CAP);
  const unsigned short* hbase = h1b + colofs;

  // prefetch self row + degree (latency hides under the edge loop)
  const uint4 selfv = *(const uint4*)(hbase + (size_t)d * DOUT + cl * 8);
  const float sd = __frsqrt_rn(1.0f + deg[d]);

  uint2 ev0; ev0.x = 0u; ev0.y = 0u;
  uint2 ev1; ev1.x = 0u; ev1.y = 0u;
  if (lane < cnt) ev0 = bucket[(size_t)d * CAP + lane];
  if (64 + lane < cnt) ev1 = bucket[(size_t)d * CAP + 64 + lane];

  float acc[8] = {};
  gather_chunk_half(acc, (int)ev0.x, __uint_as_float(ev0.y), min(cnt, 64),
                    hbase, cl, eslot);
  if (cnt > 64)
    gather_chunk_half(acc, (int)ev1.x, __uint_as_float(ev1.y), cnt - 64,
                      hbase, cl, eslot);

  // reduce across the 4 edge-slots
#pragma unroll
  for (int k = 0; k < 8; ++k) {
    acc[k] += __shfl_xor(acc[k], 16);
    acc[k] += __shfl_xor(acc[k], 32);
  }

  if (eslot == 0) {
    float4 o0v, o1v;
    o0v.x = sd * (bf_lo(selfv.x) + acc[0]);
    o0v.y = sd * (bf_hi(selfv.x) + acc[1]);
    o0v.z = sd * (bf_lo(selfv.y) + acc[2]);
    o0v.w = sd * (bf_hi(selfv.y) + acc[3]);
    o1v.x = sd * (bf_lo(selfv.z) + acc[4]);
    o1v.y = sd * (bf_hi(selfv.z) + acc[5]);
    o1v.z = sd * (bf_lo(selfv.w) + acc[6]);
    o1v.w = sd * (bf_hi(selfv.w) + acc[7]);
    float* op = out + (size_t)d * DOUT + colofs + cl * 8;
    *(float4*)op = o0v;
    *(float4*)(op + 4) = o1v;
  }
}

extern "C" void kernel_launch(void* const* d_in, const int* in_sizes, int n_in,
                              void* d_out, int out_size, void* d_ws, size_t ws_size,
                              hipStream_t stream) {
  const float* x = (const float*)d_in[0];
  const int* ei = (const int*)d_in[1];  // [2, E]: row0 = src, row1 = dst
  const float* ew = (const float*)d_in[2];
  const float* W = (const float*)d_in[3];
  float* out = (float*)d_out;

  const int n = in_sizes[0] / DIN;  // 8192
  const int E = in_sizes[2];        // 262144

  char* p = (char*)d_ws;
  auto alloc = [&](size_t bytes) {
    char* q = p;
    p += (bytes + 255) & ~(size_t)255;
    return q;
  };
  unsigned short* h1b = (unsigned short*)alloc((size_t)n * DOUT * 2);
  unsigned short* wbb = (unsigned short*)alloc((size_t)DOUT * DIN * 2);
  float* deg   = (float*)alloc((size_t)n * 4 * 2);  // deg[n] ++ cursor[n]
  int* cursor  = (int*)(deg + n);
  uint2* bucket = (uint2*)alloc((size_t)n * CAP * 8);

  const int EB = (E + 255) / 256;                  // edge blocks
  const int WB = (DOUT * DIN / 8 + 255) / 256;     // W-cvt blocks

  // deg = 0, cursor = 0 (+1 self-loop folded into rsqrt(1+deg))
  hipMemsetAsync(deg, 0, (size_t)n * 8, stream);
  k_edges<<<EB + WB, 256, 0, stream>>>(ei, ew, W, deg, cursor, bucket, wbb, E, EB);
  k_gemm_mfma<<<n / 16, 256, 0, stream>>>(x, wbb, deg, h1b);
  // two serialized half-column passes -> active h1b half stays L2-resident
  k_gather_half<<<n / 4, 256, 0, stream>>>(h1b, deg, cursor, bucket, out, 0);
  k_gather_half<<<n / 4, 256, 0, stream>>>(h1b, deg, cursor, bucket, out, 128);
}

// Round 10
// 76.650 us; speedup vs baseline: 9.1527x; 1.0286x over previous
//
#include <hip/hip_runtime.h>

static constexpr int DIN = 512;
static constexpr int DOUT = 256;
static constexpr int CAP = 128;  // max in-degree capacity (Poisson(32): P(>128) ~ 1e-17)

typedef __attribute__((ext_vector_type(8))) short short8;
typedef __attribute__((ext_vector_type(4))) float f32x4;
typedef __attribute__((ext_vector_type(2))) unsigned int u32x2;
typedef __attribute__((ext_vector_type(4))) unsigned int u32x4;

__device__ inline unsigned short f2bf(float f) {
  unsigned int b = __float_as_uint(f);
  unsigned int r = (b + 0x7fffu + ((b >> 16) & 1u)) >> 16;
  return (unsigned short)r;
}
__device__ inline float bf_lo(unsigned int packed) { return __uint_as_float(packed << 16); }
__device__ inline float bf_hi(unsigned int packed) { return __uint_as_float(packed & 0xffff0000u); }

__device__ inline short8 cvt8(const f32x4 a, const f32x4 b) {
  short8 o;
  o[0] = (short)f2bf(a[0]); o[1] = (short)f2bf(a[1]);
  o[2] = (short)f2bf(a[2]); o[3] = (short)f2bf(a[3]);
  o[4] = (short)f2bf(b[0]); o[5] = (short)f2bf(b[1]);
  o[6] = (short)f2bf(b[2]); o[7] = (short)f2bf(b[3]);
  return o;
}

// ---- K1 (after memset of deg+cursor): edges + W->bf16 ----
// blocks [0, EB): one thread per edge. blocks [EB, EB+WB): W conversion.
__global__ __launch_bounds__(256) void k_edges(
    const int* __restrict__ ei, const float* __restrict__ ew,
    const float* __restrict__ W,
    float* __restrict__ deg, int* __restrict__ cursor,
    uint2* __restrict__ bucket, unsigned short* __restrict__ wbb,
    int E, int EB) {
  const int b = blockIdx.x;
  if (b < EB) {
    int e = b * 256 + threadIdx.x;
    if (e < E) {
      int srcv = __builtin_nontemporal_load(ei + e);
      int dstv = __builtin_nontemporal_load(ei + E + e);
      float w = __builtin_nontemporal_load(ew + e);
      atomicAdd(&deg[srcv], w);
      int pos = atomicAdd(&cursor[dstv], 1);
      if (pos < CAP) {
        uint2 v;
        v.x = (unsigned)srcv;
        v.y = __float_as_uint(w);
        bucket[(size_t)dstv * CAP + pos] = v;
      }
    }
  } else {
    long i = (long)(b - EB) * 256 + threadIdx.x;  // short8 group
    const f32x4* src = (const f32x4*)(W + i * 8);
    f32x4 a = src[0], bb = src[1];
    *(short8*)(wbb + i * 8) = cvt8(a, bb);
  }
}

// ---- K2 GEMM: h1b[r][c] = bf16( rsqrt(1+deg[r]) * dot(x[r,:], W[c,:]) ) ----
// block = 4 waves; tile 16 rows x 256 cols (A read once, streamed via nt).
__global__ __launch_bounds__(256) void k_gemm_mfma(
    const float* __restrict__ x, const unsigned short* __restrict__ wbb,
    const float* __restrict__ deg, unsigned short* __restrict__ h1b) {
  const int lane = threadIdx.x & 63;
  const int wv = threadIdx.x >> 6;
  const int bm = blockIdx.x * 16;
  const int colb = wv * 64;
  const int r = lane & 15;
  const int kg = lane >> 4;
  f32x4 acc[4] = {};
  const float* arow = x + (size_t)(bm + r) * DIN + kg * 8;
  const unsigned short* brow0 = wbb + (size_t)(colb + r) * DIN + kg * 8;
#pragma unroll
  for (int k0 = 0; k0 < DIN; k0 += 32) {
    f32x4 a0 = __builtin_nontemporal_load((const f32x4*)(arow + k0));
    f32x4 a1 = __builtin_nontemporal_load((const f32x4*)(arow + k0 + 4));
    short8 av = cvt8(a0, a1);
#pragma unroll
    for (int nt = 0; nt < 4; ++nt) {
      short8 bv = *(const short8*)(brow0 + (size_t)nt * 16 * DIN + k0);
      acc[nt] = __builtin_amdgcn_mfma_f32_16x16x32_bf16(av, bv, acc[nt], 0, 0, 0);
    }
  }
#pragma unroll
  for (int i = 0; i < 4; ++i) {
    int row = bm + kg * 4 + i;
    float sr = __frsqrt_rn(1.0f + deg[row]);
#pragma unroll
    for (int nt = 0; nt < 4; ++nt) {
      h1b[(size_t)row * DOUT + colb + nt * 16 + r] = f2bf(sr * acc[nt][i]);
    }
  }
}

// ---- K3 gather: out[dst] = s[dst]*(h1s[dst] + sum_e w_e * h1s[src_e]) ----
// one wave per dst; 32 col-lanes x 2 edge-halves; edges padded to mult of 16.
// NT hints: bucket loads + out stores bypass L2 so h1b (4 MB) stays resident.
__global__ __launch_bounds__(256, 4) void k_gather(
    const unsigned short* __restrict__ h1b, const float* __restrict__ deg,
    const int* __restrict__ cursor, const uint2* __restrict__ bucket,
    float* __restrict__ out) {
  const int lane = threadIdx.x & 63;
  const int wv = threadIdx.x >> 6;
  const int dst = blockIdx.x * 4 + wv;
  const int cl = lane & 31;    // column-lane: cols cl*8 .. cl*8+7
  const int half = lane >> 5;  // which edge of a pair
  const int cnt = min(cursor[dst], CAP);

  // prefetch: self row + degree (latency hides under the edge loop)
  const u32x4 selfv = *(const u32x4*)(h1b + (size_t)dst * DOUT + cl * 8);
  const float sd = __frsqrt_rn(1.0f + deg[dst]);

  float acc[8] = {};

  for (int base = 0; base < cnt; base += 64) {
    const int c = min(64, cnt - base);
    int sv = 0;
    float wl = 0.f;
    if (lane < c) {
      u32x2 ev = __builtin_nontemporal_load(
          (const u32x2*)(bucket + (size_t)dst * CAP + base + lane));
      sv = (int)ev[0];
      wl = __uint_as_float(ev[1]);
    }
    // pairs rounded up so edge count is a multiple of 16 (pad: w=0, src=0)
    const int npair = ((c + 15) >> 4) << 3;
    for (int j = 0; j < npair; j += 8) {
      u32x4 rbuf[8];
#pragma unroll
      for (int u = 0; u < 8; ++u) {
        int src = __shfl(sv, 2 * (j + u) + half);
        rbuf[u] = *(const u32x4*)(h1b + (size_t)src * DOUT + cl * 8);
      }
#pragma unroll
      for (int u = 0; u < 8; ++u) {
        float w = __shfl(wl, 2 * (j + u) + half);
        acc[0] = fmaf(w, bf_lo(rbuf[u][0]), acc[0]);
        acc[1] = fmaf(w, bf_hi(rbuf[u][0]), acc[1]);
        acc[2] = fmaf(w, bf_lo(rbuf[u][1]), acc[2]);
        acc[3] = fmaf(w, bf_hi(rbuf[u][1]), acc[3]);
        acc[4] = fmaf(w, bf_lo(rbuf[u][2]), acc[4]);
        acc[5] = fmaf(w, bf_hi(rbuf[u][2]), acc[5]);
        acc[6] = fmaf(w, bf_lo(rbuf[u][3]), acc[6]);
        acc[7] = fmaf(w, bf_hi(rbuf[u][3]), acc[7]);
      }
    }
  }

#pragma unroll
  for (int k = 0; k < 8; ++k) acc[k] += __shfl_xor(acc[k], 32);

  if (half == 0) {
    f32x4 o0v, o1v;
    o0v[0] = sd * (bf_lo(selfv[0]) + acc[0]);
    o0v[1] = sd * (bf_hi(selfv[0]) + acc[1]);
    o0v[2] = sd * (bf_lo(selfv[1]) + acc[2]);
    o0v[3] = sd * (bf_hi(selfv[1]) + acc[3]);
    o1v[0] = sd * (bf_lo(selfv[2]) + acc[4]);
    o1v[1] = sd * (bf_hi(selfv[2]) + acc[5]);
    o1v[2] = sd * (bf_lo(selfv[3]) + acc[6]);
    o1v[3] = sd * (bf_hi(selfv[3]) + acc[7]);
    float* op = out + (size_t)dst * DOUT + cl * 8;
    __builtin_nontemporal_store(o0v, (f32x4*)op);
    __builtin_nontemporal_store(o1v, (f32x4*)(op + 4));
  }
}

extern "C" void kernel_launch(void* const* d_in, const int* in_sizes, int n_in,
                              void* d_out, int out_size, void* d_ws, size_t ws_size,
                              hipStream_t stream) {
  const float* x = (const float*)d_in[0];
  const int* ei = (const int*)d_in[1];  // [2, E]: row0 = src, row1 = dst
  const float* ew = (const float*)d_in[2];
  const float* W = (const float*)d_in[3];
  float* out = (float*)d_out;

  const int n = in_sizes[0] / DIN;  // 8192
  const int E = in_sizes[2];        // 262144

  char* p = (char*)d_ws;
  auto alloc = [&](size_t bytes) {
    char* q = p;
    p += (bytes + 255) & ~(size_t)255;
    return q;
  };
  unsigned short* h1b = (unsigned short*)alloc((size_t)n * DOUT * 2);
  unsigned short* wbb = (unsigned short*)alloc((size_t)DOUT * DIN * 2);
  float* deg   = (float*)alloc((size_t)n * 4 * 2);  // deg[n] ++ cursor[n]
  int* cursor  = (int*)(deg + n);
  uint2* bucket = (uint2*)alloc((size_t)n * CAP * 8);

  const int EB = (E + 255) / 256;                  // edge blocks
  const int WB = (DOUT * DIN / 8 + 255) / 256;     // W-cvt blocks

  // deg = 0, cursor = 0 (+1 self-loop folded into rsqrt(1+deg))
  (void)hipMemsetAsync(deg, 0, (size_t)n * 8, stream);
  k_edges<<<EB + WB, 256, 0, stream>>>(ei, ew, W, deg, cursor, bucket, wbb, E, EB);
  k_gemm_mfma<<<n / 16, 256, 0, stream>>>(x, wbb, deg, h1b);
  k_gather<<<n / 4, 256, 0, stream>>>(h1b, deg, cursor, bucket, out);
}

// Round 11
// 73.340 us; speedup vs baseline: 9.5658x; 1.0451x over previous
//
#include <hip/hip_runtime.h>

static constexpr int DIN = 512;
static constexpr int DOUT = 256;
static constexpr int CAP = 128;  // max in-degree capacity (Poisson(32): P(>128) ~ 1e-17)

typedef __attribute__((ext_vector_type(8))) short short8;
typedef __attribute__((ext_vector_type(4))) float f32x4;
typedef __attribute__((ext_vector_type(2))) unsigned int u32x2;
typedef __attribute__((ext_vector_type(4))) unsigned int u32x4;

__device__ inline unsigned short f2bf(float f) {
  unsigned int b = __float_as_uint(f);
  unsigned int r = (b + 0x7fffu + ((b >> 16) & 1u)) >> 16;
  return (unsigned short)r;
}
__device__ inline float bf_lo(unsigned int packed) { return __uint_as_float(packed << 16); }
__device__ inline float bf_hi(unsigned int packed) { return __uint_as_float(packed & 0xffff0000u); }

__device__ inline short8 cvt8(const f32x4 a, const f32x4 b) {
  short8 o;
  o[0] = (short)f2bf(a[0]); o[1] = (short)f2bf(a[1]);
  o[2] = (short)f2bf(a[2]); o[3] = (short)f2bf(a[3]);
  o[4] = (short)f2bf(b[0]); o[5] = (short)f2bf(b[1]);
  o[6] = (short)f2bf(b[2]); o[7] = (short)f2bf(b[3]);
  return o;
}

// ---- K1 prep: zero deg[n]+cursor[n]; W -> bf16 ----
__global__ __launch_bounds__(256) void k_prep(
    const float* __restrict__ W, unsigned short* __restrict__ wbb,
    int* __restrict__ dz, int n2, int wgroups) {
  const int gid = blockIdx.x * 256 + threadIdx.x;
  if (gid < n2) dz[gid] = 0;
  const int wi = gid - n2;
  if (wi >= 0 && wi < wgroups) {
    const f32x4* src = (const f32x4*)(W + (size_t)wi * 8);
    f32x4 a = src[0], b = src[1];
    *(short8*)(wbb + (size_t)wi * 8) = cvt8(a, b);
  }
}

// ---- K2 fused: edges (1/thread) + UNSCALED GEMM 16x128 half-tile/block ----
// Edge atomics are fire-and-forget except the cursor fetch; their latency
// hides under the MFMA K-loop that follows in the same wave / other waves.
__global__ __launch_bounds__(256) void k_fused(
    const int* __restrict__ ei, const float* __restrict__ ew,
    const float* __restrict__ x, const unsigned short* __restrict__ wbb,
    float* __restrict__ deg, int* __restrict__ cursor,
    uint2* __restrict__ bucket, unsigned short* __restrict__ h1b, int E) {
  // --- edge part: exactly one edge per thread (grid 1024 x 256 = E) ---
  {
    const int e = blockIdx.x * 256 + threadIdx.x;
    if (e < E) {
      int srcv = __builtin_nontemporal_load(ei + e);
      int dstv = __builtin_nontemporal_load(ei + E + e);
      float w = __builtin_nontemporal_load(ew + e);
      atomicAdd(&deg[srcv], w);
      int pos = atomicAdd(&cursor[dstv], 1);
      if (pos < CAP) {
        uint2 v;
        v.x = (unsigned)srcv;
        v.y = __float_as_uint(w);
        bucket[(size_t)dstv * CAP + pos] = v;
      }
    }
  }
  // --- GEMM part: tile rows bm..bm+15, cols colb..colb+31 per wave ---
  const int lane = threadIdx.x & 63;
  const int wv = threadIdx.x >> 6;
  const int bm = (blockIdx.x >> 1) * 16;
  const int colb = (blockIdx.x & 1) * 128 + wv * 32;
  const int r = lane & 15;
  const int kg = lane >> 4;
  f32x4 acc[2] = {};
  const float* arow = x + (size_t)(bm + r) * DIN + kg * 8;
  const unsigned short* brow = wbb + (size_t)(colb + r) * DIN + kg * 8;
#pragma unroll
  for (int k0 = 0; k0 < DIN; k0 += 32) {
    f32x4 a0 = *(const f32x4*)(arow + k0);
    f32x4 a1 = *(const f32x4*)(arow + k0 + 4);
    short8 av = cvt8(a0, a1);
    short8 b0 = *(const short8*)(brow + k0);
    short8 b1 = *(const short8*)(brow + (size_t)16 * DIN + k0);
    acc[0] = __builtin_amdgcn_mfma_f32_16x16x32_bf16(av, b0, acc[0], 0, 0, 0);
    acc[1] = __builtin_amdgcn_mfma_f32_16x16x32_bf16(av, b1, acc[1], 0, 0, 0);
  }
#pragma unroll
  for (int i = 0; i < 4; ++i) {
    int row = bm + kg * 4 + i;
    h1b[(size_t)row * DOUT + colb + r] = f2bf(acc[0][i]);
    h1b[(size_t)row * DOUT + colb + 16 + r] = f2bf(acc[1][i]);
  }
}

// ---- K3 gather: out[d] = s[d]*( s[d]*h1[d] + sum_e w_e*s[src_e]*h1[src_e] )
// h1b is UNSCALED; rsqrt(1+deg[src]) folds into the edge weight at bucket
// load. One wave per dst; 32 col-lanes x 2 edge-halves; 8-deep load batches.
__global__ __launch_bounds__(256, 4) void k_gather(
    const unsigned short* __restrict__ h1b, const float* __restrict__ deg,
    const int* __restrict__ cursor, const uint2* __restrict__ bucket,
    float* __restrict__ out) {
  const int lane = threadIdx.x & 63;
  const int wv = threadIdx.x >> 6;
  const int dst = blockIdx.x * 4 + wv;
  const int cl = lane & 31;    // column-lane: cols cl*8 .. cl*8+7
  const int half = lane >> 5;  // which edge of a pair
  const int cnt = min(cursor[dst], CAP);

  // prefetch self row + degree (latency hides under the edge loop)
  const u32x4 selfv = *(const u32x4*)(h1b + (size_t)dst * DOUT + cl * 8);
  const float sd = __frsqrt_rn(1.0f + deg[dst]);

  float acc[8] = {};

  for (int base = 0; base < cnt; base += 64) {
    const int c = min(64, cnt - base);
    int sv = 0;
    float wl = 0.f;
    if (lane < c) {
      u32x2 ev = __builtin_nontemporal_load(
          (const u32x2*)(bucket + (size_t)dst * CAP + base + lane));
      sv = (int)ev[0];
      wl = __uint_as_float(ev[1]) * __frsqrt_rn(1.0f + deg[sv]);
    }
    // pairs rounded up so edge count is a multiple of 16 (pad: w=0, src=0)
    const int npair = ((c + 15) >> 4) << 3;
    for (int j = 0; j < npair; j += 8) {
      u32x4 rbuf[8];
#pragma unroll
      for (int u = 0; u < 8; ++u) {
        int src = __shfl(sv, 2 * (j + u) + half);
        rbuf[u] = *(const u32x4*)(h1b + (size_t)src * DOUT + cl * 8);
      }
#pragma unroll
      for (int u = 0; u < 8; ++u) {
        float w = __shfl(wl, 2 * (j + u) + half);
        acc[0] = fmaf(w, bf_lo(rbuf[u][0]), acc[0]);
        acc[1] = fmaf(w, bf_hi(rbuf[u][0]), acc[1]);
        acc[2] = fmaf(w, bf_lo(rbuf[u][1]), acc[2]);
        acc[3] = fmaf(w, bf_hi(rbuf[u][1]), acc[3]);
        acc[4] = fmaf(w, bf_lo(rbuf[u][2]), acc[4]);
        acc[5] = fmaf(w, bf_hi(rbuf[u][2]), acc[5]);
        acc[6] = fmaf(w, bf_lo(rbuf[u][3]), acc[6]);
        acc[7] = fmaf(w, bf_hi(rbuf[u][3]), acc[7]);
      }
    }
  }

#pragma unroll
  for (int k = 0; k < 8; ++k) acc[k] += __shfl_xor(acc[k], 32);

  if (half == 0) {
    f32x4 o0v, o1v;
    o0v[0] = sd * fmaf(sd, bf_lo(selfv[0]), acc[0]);
    o0v[1] = sd * fmaf(sd, bf_hi(selfv[0]), acc[1]);
    o0v[2] = sd * fmaf(sd, bf_lo(selfv[1]), acc[2]);
    o0v[3] = sd * fmaf(sd, bf_hi(selfv[1]), acc[3]);
    o1v[0] = sd * fmaf(sd, bf_lo(selfv[2]), acc[4]);
    o1v[1] = sd * fmaf(sd, bf_hi(selfv[2]), acc[5]);
    o1v[2] = sd * fmaf(sd, bf_lo(selfv[3]), acc[6]);
    o1v[3] = sd * fmaf(sd, bf_hi(selfv[3]), acc[7]);
    float* op = out + (size_t)dst * DOUT + cl * 8;
    __builtin_nontemporal_store(o0v, (f32x4*)op);
    __builtin_nontemporal_store(o1v, (f32x4*)(op + 4));
  }
}

extern "C" void kernel_launch(void* const* d_in, const int* in_sizes, int n_in,
                              void* d_out, int out_size, void* d_ws, size_t ws_size,
                              hipStream_t stream) {
  const float* x = (const float*)d_in[0];
  const int* ei = (const int*)d_in[1];  // [2, E]: row0 = src, row1 = dst
  const float* ew = (const float*)d_in[2];
  const float* W = (const float*)d_in[3];
  float* out = (float*)d_out;

  const int n = in_sizes[0] / DIN;  // 8192
  const int E = in_sizes[2];        // 262144

  char* p = (char*)d_ws;
  auto alloc = [&](size_t bytes) {
    char* q = p;
    p += (bytes + 255) & ~(size_t)255;
    return q;
  };
  unsigned short* h1b = (unsigned short*)alloc((size_t)n * DOUT * 2);
  unsigned short* wbb = (unsigned short*)alloc((size_t)DOUT * DIN * 2);
  float* deg   = (float*)alloc((size_t)n * 4 * 2);  // deg[n] ++ cursor[n]
  int* cursor  = (int*)(deg + n);
  uint2* bucket = (uint2*)alloc((size_t)n * CAP * 8);

  const int n2 = 2 * n;                   // ints to zero
  const int wgroups = DOUT * DIN / 8;     // short8 groups of W
  const int prep_blocks = (n2 + wgroups + 255) / 256;

  k_prep<<<prep_blocks, 256, 0, stream>>>(W, wbb, (int*)deg, n2, wgroups);
  k_fused<<<(E + 255) / 256, 256, 0, stream>>>(ei, ew, x, wbb, deg, cursor,
                                               bucket, h1b, E);
  k_gather<<<n / 4, 256, 0, stream>>>(h1b, deg, cursor, bucket, out);
}

// Round 12
// 70.781 us; speedup vs baseline: 9.9117x; 1.0362x over previous
//
#include <hip/hip_runtime.h>

static constexpr int DIN = 512;
static constexpr int DOUT = 256;
static constexpr int CAP = 128;  // max in-degree capacity (Poisson(32): P(>128) ~ 1e-17)
static constexpr int EPT = 8;    // edges per thread in the edge pass

typedef __attribute__((ext_vector_type(8))) short short8;
typedef __attribute__((ext_vector_type(4))) float f32x4;
typedef __attribute__((ext_vector_type(2))) unsigned int u32x2;
typedef __attribute__((ext_vector_type(4))) unsigned int u32x4;

__device__ inline unsigned short f2bf(float f) {
  unsigned int b = __float_as_uint(f);
  unsigned int r = (b + 0x7fffu + ((b >> 16) & 1u)) >> 16;
  return (unsigned short)r;
}
__device__ inline float bf_lo(unsigned int packed) { return __uint_as_float(packed << 16); }
__device__ inline float bf_hi(unsigned int packed) { return __uint_as_float(packed & 0xffff0000u); }

__device__ inline short8 cvt8(const f32x4 a, const f32x4 b) {
  short8 o;
  o[0] = (short)f2bf(a[0]); o[1] = (short)f2bf(a[1]);
  o[2] = (short)f2bf(a[2]); o[3] = (short)f2bf(a[3]);
  o[4] = (short)f2bf(b[0]); o[5] = (short)f2bf(b[1]);
  o[6] = (short)f2bf(b[2]); o[7] = (short)f2bf(b[3]);
  return o;
}

// ---- K1 prep: zero deg[n]+cursor[n]; W -> bf16 ----
__global__ __launch_bounds__(256) void k_prep(
    const float* __restrict__ W, unsigned short* __restrict__ wbb,
    int* __restrict__ dz, int n2, int wgroups) {
  const int gid = blockIdx.x * 256 + threadIdx.x;
  if (gid < n2) dz[gid] = 0;
  const int wi = gid - n2;
  if (wi >= 0 && wi < wgroups) {
    const f32x4* src = (const f32x4*)(W + (size_t)wi * 8);
    f32x4 a = src[0], b = src[1];
    *(short8*)(wbb + (size_t)wi * 8) = cvt8(a, b);
  }
}

// ---- K2 work (block-specialized): ----
// blocks [0, EBLK):        edge binning, EPT edges/thread with atomic ILP
// blocks [EBLK, EBLK+GB):  UNSCALED GEMM, 16 rows x 256 cols per block
__global__ __launch_bounds__(256) void k_work(
    const int* __restrict__ ei, const float* __restrict__ ew,
    const float* __restrict__ x, const unsigned short* __restrict__ wbb,
    float* __restrict__ deg, int* __restrict__ cursor,
    uint2* __restrict__ bucket, unsigned short* __restrict__ h1b,
    int E, int EBLK) {
  const int b = blockIdx.x;
  if (b < EBLK) {
    // ---- edge pass: 256 threads x EPT edges, batched atomics ----
    const int e0 = b * 256 * EPT + threadIdx.x;
    int sv[EPT], dv[EPT];
    float wv[EPT];
#pragma unroll
    for (int u = 0; u < EPT; ++u) {
      const int e = e0 + u * 256;
      sv[u] = __builtin_nontemporal_load(ei + e);
      dv[u] = __builtin_nontemporal_load(ei + E + e);
      wv[u] = __builtin_nontemporal_load(ew + e);
    }
    int pos[EPT];
#pragma unroll
    for (int u = 0; u < EPT; ++u) pos[u] = atomicAdd(&cursor[dv[u]], 1);  // 8 in flight
#pragma unroll
    for (int u = 0; u < EPT; ++u) atomicAdd(&deg[sv[u]], wv[u]);  // fire-and-forget
#pragma unroll
    for (int u = 0; u < EPT; ++u) {
      if (pos[u] < CAP) {
        uint2 v;
        v.x = (unsigned)sv[u];
        v.y = __float_as_uint(wv[u]);
        bucket[(size_t)dv[u] * CAP + pos[u]] = v;
      }
    }
    return;
  }
  // ---- GEMM: rows bm..bm+15, wave -> 64-col strip of 256 ----
  const int g = b - EBLK;
  const int lane = threadIdx.x & 63;
  const int wv = threadIdx.x >> 6;
  const int bm = g * 16;
  const int colb = wv * 64;
  const int r = lane & 15;
  const int kg = lane >> 4;
  f32x4 acc[4] = {};
  const float* arow = x + (size_t)(bm + r) * DIN + kg * 8;
  const unsigned short* brow0 = wbb + (size_t)(colb + r) * DIN + kg * 8;
#pragma unroll
  for (int k0 = 0; k0 < DIN; k0 += 32) {
    f32x4 a0 = *(const f32x4*)(arow + k0);
    f32x4 a1 = *(const f32x4*)(arow + k0 + 4);
    short8 av = cvt8(a0, a1);
#pragma unroll
    for (int nt = 0; nt < 4; ++nt) {
      short8 bv = *(const short8*)(brow0 + (size_t)nt * 16 * DIN + k0);
      acc[nt] = __builtin_amdgcn_mfma_f32_16x16x32_bf16(av, bv, acc[nt], 0, 0, 0);
    }
  }
#pragma unroll
  for (int i = 0; i < 4; ++i) {
    int row = bm + kg * 4 + i;
#pragma unroll
    for (int nt = 0; nt < 4; ++nt) {
      h1b[(size_t)row * DOUT + colb + nt * 16 + r] = f2bf(acc[nt][i]);
    }
  }
}

// ---- K3 gather: out[d] = s[d]*( s[d]*h1[d] + sum_e w_e*s[src_e]*h1[src_e] )
// h1b is UNSCALED; rsqrt(1+deg) folds into edge weight / self term.
// One wave per dst; 32 col-lanes x 2 edge-halves; 8-deep load batches.
__global__ __launch_bounds__(256, 4) void k_gather(
    const unsigned short* __restrict__ h1b, const float* __restrict__ deg,
    const int* __restrict__ cursor, const uint2* __restrict__ bucket,
    float* __restrict__ out) {
  const int lane = threadIdx.x & 63;
  const int wv = threadIdx.x >> 6;
  const int dst = blockIdx.x * 4 + wv;
  const int cl = lane & 31;    // column-lane: cols cl*8 .. cl*8+7
  const int half = lane >> 5;  // which edge of a pair
  const int cnt = min(cursor[dst], CAP);

  const u32x4 selfv = *(const u32x4*)(h1b + (size_t)dst * DOUT + cl * 8);
  const float sd = __frsqrt_rn(1.0f + deg[dst]);

  float acc[8] = {};

  for (int base = 0; base < cnt; base += 64) {
    const int c = min(64, cnt - base);
    int sv = 0;
    float wl = 0.f;
    if (lane < c) {
      u32x2 ev = __builtin_nontemporal_load(
          (const u32x2*)(bucket + (size_t)dst * CAP + base + lane));
      sv = (int)ev[0];
      wl = __uint_as_float(ev[1]) * __frsqrt_rn(1.0f + deg[sv]);
    }
    const int npair = ((c + 15) >> 4) << 3;  // pad to mult of 16 edges
    for (int j = 0; j < npair; j += 8) {
      u32x4 rbuf[8];
#pragma unroll
      for (int u = 0; u < 8; ++u) {
        int src = __shfl(sv, 2 * (j + u) + half);
        rbuf[u] = *(const u32x4*)(h1b + (size_t)src * DOUT + cl * 8);
      }
#pragma unroll
      for (int u = 0; u < 8; ++u) {
        float w = __shfl(wl, 2 * (j + u) + half);
        acc[0] = fmaf(w, bf_lo(rbuf[u][0]), acc[0]);
        acc[1] = fmaf(w, bf_hi(rbuf[u][0]), acc[1]);
        acc[2] = fmaf(w, bf_lo(rbuf[u][1]), acc[2]);
        acc[3] = fmaf(w, bf_hi(rbuf[u][1]), acc[3]);
        acc[4] = fmaf(w, bf_lo(rbuf[u][2]), acc[4]);
        acc[5] = fmaf(w, bf_hi(rbuf[u][2]), acc[5]);
        acc[6] = fmaf(w, bf_lo(rbuf[u][3]), acc[6]);
        acc[7] = fmaf(w, bf_hi(rbuf[u][3]), acc[7]);
      }
    }
  }

#pragma unroll
  for (int k = 0; k < 8; ++k) acc[k] += __shfl_xor(acc[k], 32);

  if (half == 0) {
    f32x4 o0v, o1v;
    o0v[0] = sd * fmaf(sd, bf_lo(selfv[0]), acc[0]);
    o0v[1] = sd * fmaf(sd, bf_hi(selfv[0]), acc[1]);
    o0v[2] = sd * fmaf(sd, bf_lo(selfv[1]), acc[2]);
    o0v[3] = sd * fmaf(sd, bf_hi(selfv[1]), acc[3]);
    o1v[0] = sd * fmaf(sd, bf_lo(selfv[2]), acc[4]);
    o1v[1] = sd * fmaf(sd, bf_hi(selfv[2]), acc[5]);
    o1v[2] = sd * fmaf(sd, bf_lo(selfv[3]), acc[6]);
    o1v[3] = sd * fmaf(sd, bf_hi(selfv[3]), acc[7]);
    float* op = out + (size_t)dst * DOUT + cl * 8;
    __builtin_nontemporal_store(o0v, (f32x4*)op);
    __builtin_nontemporal_store(o1v, (f32x4*)(op + 4));
  }
}

extern "C" void kernel_launch(void* const* d_in, const int* in_sizes, int n_in,
                              void* d_out, int out_size, void* d_ws, size_t ws_size,
                              hipStream_t stream) {
  const float* x = (const float*)d_in[0];
  const int* ei = (const int*)d_in[1];  // [2, E]: row0 = src, row1 = dst
  const float* ew = (const float*)d_in[2];
  const float* W = (const float*)d_in[3];
  float* out = (float*)d_out;

  const int n = in_sizes[0] / DIN;  // 8192
  const int E = in_sizes[2];        // 262144

  char* p = (char*)d_ws;
  auto alloc = [&](size_t bytes) {
    char* q = p;
    p += (bytes + 255) & ~(size_t)255;
    return q;
  };
  unsigned short* h1b = (unsigned short*)alloc((size_t)n * DOUT * 2);
  unsigned short* wbb = (unsigned short*)alloc((size_t)DOUT * DIN * 2);
  float* deg   = (float*)alloc((size_t)n * 4 * 2);  // deg[n] ++ cursor[n]
  int* cursor  = (int*)(deg + n);
  uint2* bucket = (uint2*)alloc((size_t)n * CAP * 8);

  const int n2 = 2 * n;                   // ints to zero
  const int wgroups = DOUT * DIN / 8;     // short8 groups of W
  const int prep_blocks = (n2 + wgroups + 255) / 256;

  const int EBLK = E / (256 * EPT);       // 128 edge blocks
  const int GB = n / 16;                  // 512 GEMM blocks

  k_prep<<<prep_blocks, 256, 0, stream>>>(W, wbb, (int*)deg, n2, wgroups);
  k_work<<<EBLK + GB, 256, 0, stream>>>(ei, ew, x, wbb, deg, cursor, bucket,
                                        h1b, E, EBLK);
  k_gather<<<n / 4, 256, 0, stream>>>(h1b, deg, cursor, bucket, out);
}